// Round 5
// baseline (749.738 us; speedup 1.0000x reference)
//
#include <hip/hip_runtime.h>
#include <hip/hip_cooperative_groups.h>

namespace cg = cooperative_groups;

// CrossAttention on MI355X (gfx950), bf16 MFMA pipeline.
// ws usage: ONLY 2MB (w_o bf16 frags). Q/K/V frag buffers are hosted inside
// d_out (consumed before the final outputs are written; grid.sync() separates
// the read phase from the write phase in the cooperative attention kernel).
// Attention: grid 256 x 1024 threads (1 block/CU -- proven coop residency),
// 16 waves = 2 half-tiles x 8 col-slices, ONE barrier per head, deferred
// softmax normalization (PV on unnormalized exp2, scale at the Ohlds write).

typedef float f32x4 __attribute__((ext_vector_type(4)));
typedef short bf16x8 __attribute__((ext_vector_type(8)));
typedef short s16x4 __attribute__((ext_vector_type(4)));

#define QSCALE 0.18033688011112042f   // 0.125 * log2(e); folded into Q so P = exp2(S)

// f32 -> bf16 round-to-nearest-even
__device__ __forceinline__ short f2bf(float x) {
    union { float f; unsigned int u; } v;
    v.f = x;
    unsigned int r = v.u + 0x7FFFu + ((v.u >> 16) & 1u);
    return (short)(r >> 16);
}

// D[16x16] = A[16x32] * B[32x16] + C.  A lane: row=l&15, k=(l>>4)*8+j.
// B lane: col=l&15, k=(l>>4)*8+j.  D lane: col=l&15, row=(l>>4)*4+reg.
__device__ __forceinline__ f32x4 mfma_bf16(bf16x8 a, bf16x8 b, f32x4 c) {
    return __builtin_amdgcn_mfma_f32_16x16x32_bf16(a, b, c, 0, 0, 0);
}

// ---------------------------------------------------------------------------
// w_o [1024][1024] f32 -> bf16 B-frag-major: idx = (col>>4)*16384 + (k>>3)*128
// + (col&15)*8 + (k&7).  (2MB, the only d_ws use.)
// ---------------------------------------------------------------------------
__global__ void wo_conv_kernel(const float* __restrict__ wo, short* __restrict__ wof) {
    const int t = blockIdx.x * 256 + threadIdx.x;   // 0..131071
    const int col = t >> 7, k8 = t & 127;
    const float* p = wo + (size_t)col * 1024 + k8 * 8;
    float4 a0 = *(const float4*)p;
    float4 a1 = *(const float4*)(p + 4);
    bf16x8 v;
    v[0]=f2bf(a0.x); v[1]=f2bf(a0.y); v[2]=f2bf(a0.z); v[3]=f2bf(a0.w);
    v[4]=f2bf(a1.x); v[5]=f2bf(a1.y); v[6]=f2bf(a1.z); v[7]=f2bf(a1.w);
    *(bf16x8*)(wof + ((col >> 4) * 16384 + k8 * 128 + (col & 15) * 8)) = v;
}

// ---------------------------------------------------------------------------
// Projection GEMM: C[row,col] = sum_k A[row,k]*W[col,k] + bias[col]
// MODE 0: Q (KDIM=1024, *QSCALE, out -> Q A-frag layout)
// MODE 1: K (KDIM=768, out -> K B-frag layout)
// MODE 2: V (KDIM=768, out -> V B-frag layout, m-as-K ordering)
// Tiles: 128x128, BK=64, 4 waves (each 64x64), LDS bf16 tiles with XOR swizzle.
// ---------------------------------------------------------------------------
template <int MODE>
__global__ __launch_bounds__(256, 2) void proj_kernel(
    const float* __restrict__ Ain, const float* __restrict__ W,
    const float* __restrict__ bias, short* __restrict__ outb)
{
    constexpr int KDIM = (MODE == 1 || MODE == 2) ? 768 : 1024;
    __shared__ short Alds[128 * 64];
    __shared__ short Wlds[128 * 64];

    const int tid  = threadIdx.x;
    const int lane = tid & 63;
    const int g = lane >> 4, c = lane & 15;
    const int wid = tid >> 6;
    const int wm = wid >> 1, wn = wid & 1;
    const int bn = blockIdx.x, bm = blockIdx.y;

    const int srow = tid >> 3;        // 0..31 staging row within pass
    const int scol = (tid & 7) * 8;   // 0..56 staging col (8 elems)

    f32x4 acc[4][4] = {};

    for (int kt = 0; kt < KDIM / 64; ++kt) {
        const int k0 = kt * 64;
        __syncthreads();
        #pragma unroll
        for (int p = 0; p < 4; ++p) {
            const int r = p * 32 + srow;
            bf16x8 av, wv;
            {
                const float* ap = Ain + (size_t)(bm * 128 + r) * KDIM + k0 + scol;
                float4 a0 = *(const float4*)ap;
                float4 a1 = *(const float4*)(ap + 4);
                av[0]=f2bf(a0.x); av[1]=f2bf(a0.y); av[2]=f2bf(a0.z); av[3]=f2bf(a0.w);
                av[4]=f2bf(a1.x); av[5]=f2bf(a1.y); av[6]=f2bf(a1.z); av[7]=f2bf(a1.w);
            }
            {
                const float* wp = W + (size_t)(bn * 128 + r) * KDIM + k0 + scol;
                float4 w0 = *(const float4*)wp;
                float4 w1 = *(const float4*)(wp + 4);
                wv[0]=f2bf(w0.x); wv[1]=f2bf(w0.y); wv[2]=f2bf(w0.z); wv[3]=f2bf(w0.w);
                wv[4]=f2bf(w1.x); wv[5]=f2bf(w1.y); wv[6]=f2bf(w1.z); wv[7]=f2bf(w1.w);
            }
            const int byt = (r * 128 + scol * 2) ^ ((r & 7) << 4);  // XOR swizzle
            *(bf16x8*)((char*)Alds + byt) = av;
            *(bf16x8*)((char*)Wlds + byt) = wv;
        }
        __syncthreads();
        #pragma unroll
        for (int kc = 0; kc < 2; ++kc) {
            bf16x8 af[4], bfr[4];
            #pragma unroll
            for (int t = 0; t < 4; ++t) {
                const int ra = wm * 64 + t * 16 + c;
                af[t]  = *(const bf16x8*)((const char*)Alds +
                          ((ra * 128 + (kc * 32 + g * 8) * 2) ^ ((ra & 7) << 4)));
                const int rb = wn * 64 + t * 16 + c;
                bfr[t] = *(const bf16x8*)((const char*)Wlds +
                          ((rb * 128 + (kc * 32 + g * 8) * 2) ^ ((rb & 7) << 4)));
            }
            #pragma unroll
            for (int i = 0; i < 4; ++i)
                #pragma unroll
                for (int j = 0; j < 4; ++j)
                    acc[i][j] = mfma_bf16(af[i], bfr[j], acc[i][j]);
        }
    }

    // epilogue -> frag-major layouts
    #pragma unroll
    for (int j = 0; j < 4; ++j) {
        const int col = bn * 128 + wn * 64 + j * 16 + c;
        const float bv = bias[col];
        #pragma unroll
        for (int i = 0; i < 4; ++i) {
            #pragma unroll
            for (int r = 0; r < 4; ++r) {
                const int row = bm * 128 + wm * 64 + i * 16 + g * 4 + r;
                float v = acc[i][j][r] + bv;
                if constexpr (MODE == 0) v *= QSCALE;
                const int b = row >> 10, s = row & 1023;
                const int h = col >> 6,  d = col & 63;
                const size_t base = (size_t)(b * 16 + h) * 65536;
                size_t idx;
                if constexpr (MODE == 0)       // A-frag: [ntile][kc][g][c][j]
                    idx = base + (size_t)((s >> 4) * 1024 + (d >> 5) * 512 +
                          ((d >> 3) & 3) * 128 + (s & 15) * 8 + (d & 7));
                else if constexpr (MODE == 1)  // B-frag: [mtile][dchunk][c][j]
                    idx = base + (size_t)((s >> 4) * 1024 + (d >> 3) * 128 +
                          (s & 15) * 8 + (d & 7));
                else                           // V B-frag: [m32][dtile][g][c][j] (k = m)
                    idx = base + (size_t)((s >> 5) * 2048 + (d >> 4) * 512 +
                          ((s >> 3) & 3) * 128 + (d & 15) * 8 + (s & 7));
                outb[idx] = f2bf(v);
            }
        }
    }
}

// ---------------------------------------------------------------------------
// Cooperative attention + fused O-projection.
// Block = (batch b, 32-row q-tile), 1024 threads (16 waves), grid 256
// (1 block/CU -- same residency regime as the round-3 launch that worked).
// Wave w: half = w>>3 (16-row subtile), wc = w&7 (128 score cols).
// Deferred-normalization softmax, ONE barrier per head, red/oacc parity-dbuf.
// Phase 2 after grid.sync(): attn-mean write (clobbers qf/kf hosting) +
// tail GEMM out = Oh @ w_o^T + b_o (clobbers vf hosting).
// ---------------------------------------------------------------------------
__global__ __launch_bounds__(1024, 4) void attn_kernel(
    const short* Qf, const short* Kf, const short* Vf,
    const short* Wof, const float* bo, float* outp)
{
    __shared__ alignas(16) short Ohlds[32 * 1024];     // 64KB attn out, swizzled
    __shared__ alignas(16) float pbuf[16][16 * 36];    // 36.9KB per-wave P bounce
    __shared__ alignas(16) float red[2][2][16][8];     // 2KB row-sum partials
    __shared__ alignas(16) float oacc[2][2][16][68];   // 17.4KB O accum

    const int tid  = threadIdx.x;
    const int lane = tid & 63;
    const int w = tid >> 6;                  // 0..15
    const int half = w >> 3, wc = w & 7;
    const int g = lane >> 4, c = lane & 15;
    const int b = blockIdx.x >> 5, qt = blockIdx.x & 31;

    if (tid < 512) {
        const int zn = tid >> 4, zd = (tid & 15) * 4;  // zn: 0..31 rows
        *(f32x4*)&oacc[0][zn >> 4][zn & 15][zd] = (f32x4){0.f, 0.f, 0.f, 0.f};
        *(f32x4*)&oacc[1][zn >> 4][zn & 15][zd] = (f32x4){0.f, 0.f, 0.f, 0.f};
    }
    __syncthreads();

    f32x4 am[8] = {};  // sum over heads of normalized P (attn.mean), wave's slice

    for (int h = 0; h < 16; ++h) {
        const int par = h & 1;
        const size_t hb = (size_t)(b * 16 + h) * 65536;

        bf16x8 qfr[2];
        #pragma unroll
        for (int kc = 0; kc < 2; ++kc)
            qfr[kc] = *(const bf16x8*)(Qf + hb +
                (size_t)((qt * 2 + half) * 1024 + kc * 512 + g * 128 + c * 8));

        // S = Q K^T (scaled): wave's 128-col slice, 16 q-rows
        f32x4 p[8] = {};
        #pragma unroll
        for (int mt = 0; mt < 8; ++mt) {
            const int mtile = wc * 8 + mt;
            #pragma unroll
            for (int kc = 0; kc < 2; ++kc) {
                bf16x8 kfr = *(const bf16x8*)(Kf + hb +
                    (size_t)(mtile * 1024 + (kc * 4 + g) * 128 + c * 8));
                p[mt] = mfma_bf16(qfr[kc], kfr, p[mt]);
            }
        }

        // exp2 (clamped) + per-lane partial row sums
        f32x4 rs = {};
        #pragma unroll
        for (int mt = 0; mt < 8; ++mt) {
            f32x4 v = p[mt];
            #pragma unroll
            for (int r = 0; r < 4; ++r)
                v[r] = exp2f(fminf(fmaxf(v[r], -60.f), 60.f));
            p[mt] = v;
            rs += v;
        }
        #pragma unroll
        for (int off = 1; off < 16; off <<= 1)
            #pragma unroll
            for (int r = 0; r < 4; ++r)
                rs[r] += __shfl_xor(rs[r], off);
        if (c == 0) {
            #pragma unroll
            for (int r = 0; r < 4; ++r)
                red[par][half][g * 4 + r][wc] = rs[r];
        }

        // PV on UNNORMALIZED P: bounce 16x32 chunks through per-wave LDS
        float* pb = pbuf[w];
        f32x4 oa[4] = {};
        #pragma unroll
        for (int ks = 0; ks < 4; ++ks) {
            #pragma unroll
            for (int m2 = 0; m2 < 2; ++m2)
                #pragma unroll
                for (int r = 0; r < 4; ++r)
                    pb[(g * 4 + r) * 36 + m2 * 16 + c] = p[ks * 2 + m2][r];
            asm volatile("s_waitcnt lgkmcnt(0)" ::: "memory");
            f32x4 lo = *(const f32x4*)&pb[c * 36 + g * 8];
            f32x4 hi = *(const f32x4*)&pb[c * 36 + g * 8 + 4];
            bf16x8 pa;
            pa[0]=f2bf(lo[0]); pa[1]=f2bf(lo[1]); pa[2]=f2bf(lo[2]); pa[3]=f2bf(lo[3]);
            pa[4]=f2bf(hi[0]); pa[5]=f2bf(hi[1]); pa[6]=f2bf(hi[2]); pa[7]=f2bf(hi[3]);
            #pragma unroll
            for (int dt = 0; dt < 4; ++dt) {
                bf16x8 vfr = *(const bf16x8*)(Vf + hb +
                    (size_t)(((wc * 4 + ks) * 4 + dt) * 512 + g * 128 + c * 8));
                oa[dt] = mfma_bf16(pa, vfr, oa[dt]);
            }
        }
        #pragma unroll
        for (int dt = 0; dt < 4; ++dt)
            #pragma unroll
            for (int r = 0; r < 4; ++r)
                atomicAdd(&oacc[par][half][g * 4 + r][dt * 16 + c], oa[dt][r]);

        __syncthreads();   // the ONE barrier per head

        // per-lane rinv for rows g*4+r (vector reads of all 8 wave partials)
        f32x4 rv;
        #pragma unroll
        for (int r = 0; r < 4; ++r) {
            f32x4 s0 = *(const f32x4*)&red[par][half][g * 4 + r][0];
            f32x4 s1 = *(const f32x4*)&red[par][half][g * 4 + r][4];
            f32x4 ss = s0 + s1;
            rv[r] = 1.0f / (ss[0] + ss[1] + ss[2] + ss[3]);
        }
        #pragma unroll
        for (int mt = 0; mt < 8; ++mt)
            am[mt] += p[mt] * rv;

        // O normalize + stage to Ohlds (threads 0..511), re-zero oacc slot
        if (tid < 512) {
            const int zn = tid >> 4, zd = (tid & 15) * 4;
            const int zh = zn >> 4, zr = zn & 15;
            f32x4 s0 = *(const f32x4*)&red[par][zh][zr][0];
            f32x4 s1 = *(const f32x4*)&red[par][zh][zr][4];
            f32x4 ss = s0 + s1;
            const float inv = 1.0f / (ss[0] + ss[1] + ss[2] + ss[3]);
            f32x4 ov = *(const f32x4*)&oacc[par][zh][zr][zd];
            *(f32x4*)&oacc[par][zh][zr][zd] = (f32x4){0.f, 0.f, 0.f, 0.f};
            s16x4 pk;
            pk[0] = f2bf(ov[0] * inv); pk[1] = f2bf(ov[1] * inv);
            pk[2] = f2bf(ov[2] * inv); pk[3] = f2bf(ov[3] * inv);
            unsigned byt = (unsigned)(zn * 2048 + (h * 64 + zd) * 2);
            byt ^= (unsigned)((zn & 7) << 4);          // XOR swizzle
            *(s16x4*)((char*)Ohlds + byt) = pk;
        }
    }

    __syncthreads();
    // ---- all blocks done reading qf/kf/vf hosted in d_out ----
    cg::this_grid().sync();

    // attn.mean(heads) -> out1 (clobbers qf/kf hosting)
    float* aout = outp + 8388608 + (size_t)b * 1048576;
    #pragma unroll
    for (int mt = 0; mt < 8; ++mt)
        #pragma unroll
        for (int r = 0; r < 4; ++r) {
            const int n = qt * 32 + half * 16 + g * 4 + r;
            const int m = wc * 128 + mt * 16 + c;
            aout[(size_t)n * 1024 + m] = am[mt][r] * 0.0625f;
        }

    // tail GEMM: out[32 rows][1024] = Ohlds(32x1024) @ w_o^T + b_o.
    // wave w: rows half*16..+16, cols wc*128..+128 (clobbers vf hosting).
    f32x4 acc2[8] = {};
    for (int kt = 0; kt < 32; ++kt) {
        const int row = half * 16 + c;
        unsigned byt = (unsigned)(row * 2048 + (kt * 32 + g * 8) * 2);
        byt ^= (unsigned)((row & 7) << 4);
        bf16x8 afr = *(const bf16x8*)((const char*)Ohlds + byt);
        #pragma unroll
        for (int ct = 0; ct < 8; ++ct) {
            bf16x8 bfr = *(const bf16x8*)(Wof +
                ((wc * 8 + ct) * 16384 + (kt * 4 + g) * 128 + c * 8));
            acc2[ct] = mfma_bf16(afr, bfr, acc2[ct]);
        }
    }
    #pragma unroll
    for (int ct = 0; ct < 8; ++ct) {
        const int col = wc * 128 + ct * 16 + c;
        const float bv = bo[col];
        #pragma unroll
        for (int r = 0; r < 4; ++r) {
            const int n = qt * 32 + half * 16 + g * 4 + r;
            outp[(size_t)(b * 1024 + n) * 1024 + col] = acc2[ct][r] + bv;
        }
    }
}

extern "C" void kernel_launch(void* const* d_in, const int* in_sizes, int n_in,
                              void* d_out, int out_size, void* d_ws, size_t ws_size,
                              hipStream_t stream)
{
    (void)in_sizes; (void)n_in; (void)out_size; (void)ws_size;
    const float* query = (const float*)d_in[0];
    const float* key   = (const float*)d_in[1];
    const float* value = (const float*)d_in[2];
    const float* w_q = (const float*)d_in[3];
    const float* b_q = (const float*)d_in[4];
    const float* w_k = (const float*)d_in[5];
    const float* b_k = (const float*)d_in[6];
    const float* w_v = (const float*)d_in[7];
    const float* b_v = (const float*)d_in[8];
    const float* w_o = (const float*)d_in[9];
    const float* b_o = (const float*)d_in[10];

    float* out = (float*)d_out;              // out0 [0,8M) floats; out1 [8M,16M)
    short* vf  = (short*)d_out;              // V frags hosted in out0 (16.78MB)
    short* qf  = (short*)(out + 8388608);    // Q frags hosted in out1 lower half
    short* kf  = qf + 8388608;               // K frags hosted in out1 upper half
    short* wof = (short*)d_ws;               // w_o bf16 frags (2MB — only ws use)

    wo_conv_kernel<<<dim3(512), 256, 0, stream>>>(w_o, wof);

    dim3 pgrid(8, 64);  // x = col tile (1024/128), y = row tile (8192/128)
    proj_kernel<0><<<pgrid, 256, 0, stream>>>(query, w_q, b_q, qf);
    proj_kernel<1><<<pgrid, 256, 0, stream>>>(key,   w_k, b_k, kf);
    proj_kernel<2><<<pgrid, 256, 0, stream>>>(value, w_v, b_v, vf);

    void* args[] = { (void*)&qf, (void*)&kf, (void*)&vf,
                     (void*)&wof, (void*)&b_o, (void*)&out };
    hipLaunchCooperativeKernel(attn_kernel, dim3(256), dim3(1024), args, 0u, stream);
}

// Round 6
// 520.971 us; speedup vs baseline: 1.4391x; 1.4391x over previous
//
#include <hip/hip_runtime.h>
#include <hip/hip_cooperative_groups.h>

namespace cg = cooperative_groups;

// CrossAttention on MI355X (gfx950), bf16 MFMA pipeline.
// ws usage: ONLY 2MB (w_o bf16 frags). Q/K/V frag buffers are hosted inside
// d_out (consumed before the final outputs are written; grid.sync() separates
// the read phase from the write phase in the cooperative attention kernel).
// Attention: grid 256 x 1024 threads (1 block/CU), 16 waves = 2 half x 8 col
// slices. Per head: batched K loads + prefetched next-head Q/K frags,
// PV with V-hoisted loads and bf16 P-bounce, per-wave O slots (NO atomics),
// two barriers per head.

typedef float f32x4 __attribute__((ext_vector_type(4)));
typedef short bf16x8 __attribute__((ext_vector_type(8)));
typedef short s16x4 __attribute__((ext_vector_type(4)));

#define QSCALE 0.18033688011112042f   // 0.125 * log2(e); folded into Q so P = exp2(S)
#define PF 4                          // K-frags prefetched for next head

// f32 -> bf16 round-to-nearest-even
__device__ __forceinline__ short f2bf(float x) {
    union { float f; unsigned int u; } v;
    v.f = x;
    unsigned int r = v.u + 0x7FFFu + ((v.u >> 16) & 1u);
    return (short)(r >> 16);
}

// D[16x16] = A[16x32] * B[32x16] + C.  A lane: row=l&15, k=(l>>4)*8+j.
// B lane: col=l&15, k=(l>>4)*8+j.  D lane: col=l&15, row=(l>>4)*4+reg.
__device__ __forceinline__ f32x4 mfma_bf16(bf16x8 a, bf16x8 b, f32x4 c) {
    return __builtin_amdgcn_mfma_f32_16x16x32_bf16(a, b, c, 0, 0, 0);
}

// ---------------------------------------------------------------------------
// w_o [1024][1024] f32 -> bf16 B-frag-major (2MB, the only d_ws use).
// ---------------------------------------------------------------------------
__global__ void wo_conv_kernel(const float* __restrict__ wo, short* __restrict__ wof) {
    const int t = blockIdx.x * 256 + threadIdx.x;   // 0..131071
    const int col = t >> 7, k8 = t & 127;
    const float* p = wo + (size_t)col * 1024 + k8 * 8;
    float4 a0 = *(const float4*)p;
    float4 a1 = *(const float4*)(p + 4);
    bf16x8 v;
    v[0]=f2bf(a0.x); v[1]=f2bf(a0.y); v[2]=f2bf(a0.z); v[3]=f2bf(a0.w);
    v[4]=f2bf(a1.x); v[5]=f2bf(a1.y); v[6]=f2bf(a1.z); v[7]=f2bf(a1.w);
    *(bf16x8*)(wof + ((col >> 4) * 16384 + k8 * 128 + (col & 15) * 8)) = v;
}

// ---------------------------------------------------------------------------
// Projection GEMM: C[row,col] = sum_k A[row,k]*W[col,k] + bias[col]
// MODE 0: Q (KDIM=1024, *QSCALE, -> Q A-frag)   MODE 1: K (768, -> K B-frag)
// MODE 2: V (768, -> V B-frag, m-as-K)
// ---------------------------------------------------------------------------
template <int MODE>
__global__ __launch_bounds__(256, 2) void proj_kernel(
    const float* __restrict__ Ain, const float* __restrict__ W,
    const float* __restrict__ bias, short* __restrict__ outb)
{
    constexpr int KDIM = (MODE == 1 || MODE == 2) ? 768 : 1024;
    __shared__ short Alds[128 * 64];
    __shared__ short Wlds[128 * 64];

    const int tid  = threadIdx.x;
    const int lane = tid & 63;
    const int g = lane >> 4, c = lane & 15;
    const int wid = tid >> 6;
    const int wm = wid >> 1, wn = wid & 1;
    const int bn = blockIdx.x, bm = blockIdx.y;

    const int srow = tid >> 3;
    const int scol = (tid & 7) * 8;

    f32x4 acc[4][4] = {};

    for (int kt = 0; kt < KDIM / 64; ++kt) {
        const int k0 = kt * 64;
        __syncthreads();
        #pragma unroll
        for (int p = 0; p < 4; ++p) {
            const int r = p * 32 + srow;
            bf16x8 av, wv;
            {
                const float* ap = Ain + (size_t)(bm * 128 + r) * KDIM + k0 + scol;
                float4 a0 = *(const float4*)ap;
                float4 a1 = *(const float4*)(ap + 4);
                av[0]=f2bf(a0.x); av[1]=f2bf(a0.y); av[2]=f2bf(a0.z); av[3]=f2bf(a0.w);
                av[4]=f2bf(a1.x); av[5]=f2bf(a1.y); av[6]=f2bf(a1.z); av[7]=f2bf(a1.w);
            }
            {
                const float* wp = W + (size_t)(bn * 128 + r) * KDIM + k0 + scol;
                float4 w0 = *(const float4*)wp;
                float4 w1 = *(const float4*)(wp + 4);
                wv[0]=f2bf(w0.x); wv[1]=f2bf(w0.y); wv[2]=f2bf(w0.z); wv[3]=f2bf(w0.w);
                wv[4]=f2bf(w1.x); wv[5]=f2bf(w1.y); wv[6]=f2bf(w1.z); wv[7]=f2bf(w1.w);
            }
            const int byt = (r * 128 + scol * 2) ^ ((r & 7) << 4);
            *(bf16x8*)((char*)Alds + byt) = av;
            *(bf16x8*)((char*)Wlds + byt) = wv;
        }
        __syncthreads();
        #pragma unroll
        for (int kc = 0; kc < 2; ++kc) {
            bf16x8 af[4], bfr[4];
            #pragma unroll
            for (int t = 0; t < 4; ++t) {
                const int ra = wm * 64 + t * 16 + c;
                af[t]  = *(const bf16x8*)((const char*)Alds +
                          ((ra * 128 + (kc * 32 + g * 8) * 2) ^ ((ra & 7) << 4)));
                const int rb = wn * 64 + t * 16 + c;
                bfr[t] = *(const bf16x8*)((const char*)Wlds +
                          ((rb * 128 + (kc * 32 + g * 8) * 2) ^ ((rb & 7) << 4)));
            }
            #pragma unroll
            for (int i = 0; i < 4; ++i)
                #pragma unroll
                for (int j = 0; j < 4; ++j)
                    acc[i][j] = mfma_bf16(af[i], bfr[j], acc[i][j]);
        }
    }

    #pragma unroll
    for (int j = 0; j < 4; ++j) {
        const int col = bn * 128 + wn * 64 + j * 16 + c;
        const float bv = bias[col];
        #pragma unroll
        for (int i = 0; i < 4; ++i) {
            #pragma unroll
            for (int r = 0; r < 4; ++r) {
                const int row = bm * 128 + wm * 64 + i * 16 + g * 4 + r;
                float v = acc[i][j][r] + bv;
                if constexpr (MODE == 0) v *= QSCALE;
                const int b = row >> 10, s = row & 1023;
                const int h = col >> 6,  d = col & 63;
                const size_t base = (size_t)(b * 16 + h) * 65536;
                size_t idx;
                if constexpr (MODE == 0)       // A-frag: [ntile][kc][g][c][j]
                    idx = base + (size_t)((s >> 4) * 1024 + (d >> 5) * 512 +
                          ((d >> 3) & 3) * 128 + (s & 15) * 8 + (d & 7));
                else if constexpr (MODE == 1)  // B-frag: [mtile][dchunk][c][j]
                    idx = base + (size_t)((s >> 4) * 1024 + (d >> 3) * 128 +
                          (s & 15) * 8 + (d & 7));
                else                           // V B-frag: [m32][dtile][g][c][j]
                    idx = base + (size_t)((s >> 5) * 2048 + (d >> 4) * 512 +
                          ((s >> 3) & 3) * 128 + (d & 15) * 8 + (s & 7));
                outb[idx] = f2bf(v);
            }
        }
    }
}

// ---------------------------------------------------------------------------
// Cooperative attention + fused O-projection.
// Block = (batch b, 32-row q-tile), 1024 threads (16 waves), grid 256.
// Wave w: half = w>>3 (16-row subtile), wc = w&7 (128 score cols).
// Deferred-normalization softmax; NO LDS atomics (per-wave oasl slots);
// next-head Q/K prefetch issued before barrier 1; two barriers per head.
// ---------------------------------------------------------------------------
__global__ __launch_bounds__(1024, 4) void attn_kernel(
    const short* Qf, const short* Kf, const short* Vf,
    const short* Wof, const float* bo, float* outp)
{
    __shared__ alignas(16) short Ohlds[32 * 1024];    // 64KB attn out, swizzled
    __shared__ alignas(16) short pbufs[16 * 16 * 40]; // 20.5KB bf16 P bounce
    __shared__ alignas(16) float oasl[16][16][68];    // 69.6KB per-wave O slots
    __shared__ alignas(16) float red[2][16][8];       // 1KB row-sum partials

    const int tid  = threadIdx.x;
    const int lane = tid & 63;
    const int w = tid >> 6;                  // 0..15
    const int half = w >> 3, wc = w & 7;
    const int g = lane >> 4, c = lane & 15;
    const int b = blockIdx.x >> 5, qt = blockIdx.x & 31;

    f32x4 am[8] = {};  // sum over heads of normalized P (attn.mean), wave slice

    // prologue: load head-0 Q frags + first PF K frags (kc=0)
    bf16x8 qfr[2], kfr0[8];
    {
        const size_t hb0 = (size_t)(b * 16) * 65536;
        #pragma unroll
        for (int kc = 0; kc < 2; ++kc)
            qfr[kc] = *(const bf16x8*)(Qf + hb0 +
                (size_t)((qt * 2 + half) * 1024 + kc * 512 + g * 128 + c * 8));
        #pragma unroll
        for (int mt = 0; mt < PF; ++mt)
            kfr0[mt] = *(const bf16x8*)(Kf + hb0 +
                (size_t)((wc * 8 + mt) * 1024 + g * 128 + c * 8));
    }

    for (int h = 0; h < 16; ++h) {
        const size_t hb = (size_t)(b * 16 + h) * 65536;

        // finish K loads for this head (batched issue, then MFMAs)
        bf16x8 kfr1[8];
        #pragma unroll
        for (int mt = PF; mt < 8; ++mt)
            kfr0[mt] = *(const bf16x8*)(Kf + hb +
                (size_t)((wc * 8 + mt) * 1024 + g * 128 + c * 8));
        #pragma unroll
        for (int mt = 0; mt < 8; ++mt)
            kfr1[mt] = *(const bf16x8*)(Kf + hb +
                (size_t)((wc * 8 + mt) * 1024 + (4 + g) * 128 + c * 8));

        f32x4 p[8] = {};
        #pragma unroll
        for (int mt = 0; mt < 8; ++mt)
            p[mt] = mfma_bf16(qfr[0], kfr0[mt], p[mt]);
        #pragma unroll
        for (int mt = 0; mt < 8; ++mt)
            p[mt] = mfma_bf16(qfr[1], kfr1[mt], p[mt]);

        // exp2 (clamped) + per-lane partial row sums
        f32x4 rs = {};
        #pragma unroll
        for (int mt = 0; mt < 8; ++mt) {
            f32x4 v = p[mt];
            #pragma unroll
            for (int r = 0; r < 4; ++r)
                v[r] = exp2f(fminf(fmaxf(v[r], -60.f), 60.f));
            p[mt] = v;
            rs += v;
        }
        #pragma unroll
        for (int off = 1; off < 16; off <<= 1)
            #pragma unroll
            for (int r = 0; r < 4; ++r)
                rs[r] += __shfl_xor(rs[r], off);
        if (c == 0) {
            #pragma unroll
            for (int r = 0; r < 4; ++r)
                red[half][g * 4 + r][wc] = rs[r];
        }

        // PV on UNNORMALIZED P: V loads hoisted above the bf16 bounce
        short* pbs = pbufs + w * 640;
        f32x4 oa[4] = {};
        #pragma unroll
        for (int ks = 0; ks < 4; ++ks) {
            bf16x8 vfr[4];
            #pragma unroll
            for (int dt = 0; dt < 4; ++dt)
                vfr[dt] = *(const bf16x8*)(Vf + hb +
                    (size_t)(((wc * 4 + ks) * 4 + dt) * 512 + g * 128 + c * 8));
            #pragma unroll
            for (int m2 = 0; m2 < 2; ++m2)
                #pragma unroll
                for (int r = 0; r < 4; ++r)
                    pbs[(g * 4 + r) * 40 + m2 * 16 + c] = f2bf(p[ks * 2 + m2][r]);
            asm volatile("s_waitcnt lgkmcnt(0)" ::: "memory");
            bf16x8 pa = *(const bf16x8*)&pbs[c * 40 + g * 8];
            #pragma unroll
            for (int dt = 0; dt < 4; ++dt)
                oa[dt] = mfma_bf16(pa, vfr[dt], oa[dt]);
        }
        // per-wave O slot (plain stores, no atomics)
        #pragma unroll
        for (int dt = 0; dt < 4; ++dt)
            #pragma unroll
            for (int r = 0; r < 4; ++r)
                oasl[w][g * 4 + r][dt * 16 + c] = oa[dt][r];

        // prefetch next head's Q frags + first PF K frags (hide under barrier)
        if (h < 15) {
            const size_t hbN = hb + 65536;
            #pragma unroll
            for (int kc = 0; kc < 2; ++kc)
                qfr[kc] = *(const bf16x8*)(Qf + hbN +
                    (size_t)((qt * 2 + half) * 1024 + kc * 512 + g * 128 + c * 8));
            #pragma unroll
            for (int mt = 0; mt < PF; ++mt)
                kfr0[mt] = *(const bf16x8*)(Kf + hbN +
                    (size_t)((wc * 8 + mt) * 1024 + g * 128 + c * 8));
        }

        __syncthreads();   // barrier 1: red + oasl visible

        // per-lane rinv for rows g*4+r
        f32x4 rv;
        #pragma unroll
        for (int r = 0; r < 4; ++r) {
            f32x4 s0 = *(const f32x4*)&red[half][g * 4 + r][0];
            f32x4 s1 = *(const f32x4*)&red[half][g * 4 + r][4];
            f32x4 ss = s0 + s1;
            rv[r] = 1.0f / (ss[0] + ss[1] + ss[2] + ss[3]);
        }
        #pragma unroll
        for (int mt = 0; mt < 8; ++mt)
            am[mt] += p[mt] * rv;

        // O tree-sum over 8 wave slots + normalize + stage to Ohlds
        if (tid < 512) {
            const int zn = tid >> 4, zd = (tid & 15) * 4;
            const int zh = zn >> 4, zr = zn & 15;
            f32x4 s0 = *(const f32x4*)&red[zh][zr][0];
            f32x4 s1 = *(const f32x4*)&red[zh][zr][4];
            f32x4 ss = s0 + s1;
            const float inv = 1.0f / (ss[0] + ss[1] + ss[2] + ss[3]);
            f32x4 ov = {0.f, 0.f, 0.f, 0.f};
            #pragma unroll
            for (int i = 0; i < 8; ++i)
                ov += *(const f32x4*)&oasl[zh * 8 + i][zr][zd];
            s16x4 pk;
            pk[0] = f2bf(ov[0] * inv); pk[1] = f2bf(ov[1] * inv);
            pk[2] = f2bf(ov[2] * inv); pk[3] = f2bf(ov[3] * inv);
            unsigned byt = (unsigned)(zn * 2048 + (h * 64 + zd) * 2);
            byt ^= (unsigned)((zn & 7) << 4);          // XOR swizzle
            *(s16x4*)((char*)Ohlds + byt) = pk;
        }

        __syncthreads();   // barrier 2: reads done before next head's writes
    }

    // ---- all blocks done reading qf/kf/vf hosted in d_out ----
    cg::this_grid().sync();

    // attn.mean(heads) -> out1 (clobbers qf/kf hosting)
    float* aout = outp + 8388608 + (size_t)b * 1048576;
    #pragma unroll
    for (int mt = 0; mt < 8; ++mt)
        #pragma unroll
        for (int r = 0; r < 4; ++r) {
            const int n = qt * 32 + half * 16 + g * 4 + r;
            const int m = wc * 128 + mt * 16 + c;
            aout[(size_t)n * 1024 + m] = am[mt][r] * 0.0625f;
        }

    // tail GEMM: out[32 rows][1024] = Ohlds(32x1024) @ w_o^T + b_o.
    f32x4 acc2[8] = {};
    for (int kt = 0; kt < 32; ++kt) {
        const int row = half * 16 + c;
        unsigned byt = (unsigned)(row * 2048 + (kt * 32 + g * 8) * 2);
        byt ^= (unsigned)((row & 7) << 4);
        bf16x8 afr = *(const bf16x8*)((const char*)Ohlds + byt);
        #pragma unroll
        for (int ct = 0; ct < 8; ++ct) {
            bf16x8 bfr = *(const bf16x8*)(Wof +
                ((wc * 8 + ct) * 16384 + (kt * 4 + g) * 128 + c * 8));
            acc2[ct] = mfma_bf16(afr, bfr, acc2[ct]);
        }
    }
    #pragma unroll
    for (int ct = 0; ct < 8; ++ct) {
        const int col = wc * 128 + ct * 16 + c;
        const float bv = bo[col];
        #pragma unroll
        for (int r = 0; r < 4; ++r) {
            const int n = qt * 32 + half * 16 + g * 4 + r;
            outp[(size_t)(b * 1024 + n) * 1024 + col] = acc2[ct][r] + bv;
        }
    }
}

extern "C" void kernel_launch(void* const* d_in, const int* in_sizes, int n_in,
                              void* d_out, int out_size, void* d_ws, size_t ws_size,
                              hipStream_t stream)
{
    (void)in_sizes; (void)n_in; (void)out_size; (void)ws_size;
    const float* query = (const float*)d_in[0];
    const float* key   = (const float*)d_in[1];
    const float* value = (const float*)d_in[2];
    const float* w_q = (const float*)d_in[3];
    const float* b_q = (const float*)d_in[4];
    const float* w_k = (const float*)d_in[5];
    const float* b_k = (const float*)d_in[6];
    const float* w_v = (const float*)d_in[7];
    const float* b_v = (const float*)d_in[8];
    const float* w_o = (const float*)d_in[9];
    const float* b_o = (const float*)d_in[10];

    float* out = (float*)d_out;              // out0 [0,8M) floats; out1 [8M,16M)
    short* vf  = (short*)d_out;              // V frags hosted in out0 (16.78MB)
    short* qf  = (short*)(out + 8388608);    // Q frags hosted in out1 lower half
    short* kf  = qf + 8388608;               // K frags hosted in out1 upper half
    short* wof = (short*)d_ws;               // w_o bf16 frags (2MB — only ws use)

    wo_conv_kernel<<<dim3(512), 256, 0, stream>>>(w_o, wof);

    dim3 pgrid(8, 64);
    proj_kernel<0><<<pgrid, 256, 0, stream>>>(query, w_q, b_q, qf);
    proj_kernel<1><<<pgrid, 256, 0, stream>>>(key,   w_k, b_k, kf);
    proj_kernel<2><<<pgrid, 256, 0, stream>>>(value, w_v, b_v, vf);

    void* args[] = { (void*)&qf, (void*)&kf, (void*)&vf,
                     (void*)&wof, (void*)&b_o, (void*)&out };
    hipLaunchCooperativeKernel(attn_kernel, dim3(256), dim3(1024), args, 0u, stream);
}

// Round 7
// 375.674 us; speedup vs baseline: 1.9957x; 1.3868x over previous
//
#include <hip/hip_runtime.h>
#include <hip/hip_cooperative_groups.h>

namespace cg = cooperative_groups;

// CrossAttention on MI355X (gfx950), bf16 MFMA pipeline.
// ws usage: ONLY 2MB (w_o bf16 frags). Q/K/V frag buffers are hosted inside
// d_out (consumed before the final outputs are written; grid.sync() separates
// the read phase from the write phase in the cooperative attention kernel).
// Attention: grid 256 x 512 threads (8 waves, 1 block/CU, 256-VGPR budget --
// NO spills, round 6 was spill-traffic-bound at 730MB/dispatch).
// Wave w owns score cols [w*128,+128) for ALL 32 q-rows. Batched K loads,
// V-hoisted PV, bf16 P-bounce, per-wave O slots (no atomics), cross-barrier
// prefetch, two barriers per head. XCD swizzle: b = bid&7.

typedef float f32x4 __attribute__((ext_vector_type(4)));
typedef short bf16x8 __attribute__((ext_vector_type(8)));
typedef short s16x4 __attribute__((ext_vector_type(4)));

#define QSCALE 0.18033688011112042f   // 0.125 * log2(e); folded into Q so P = exp2(S)
#define PF 4                          // K-frags prefetched for next head

// f32 -> bf16 round-to-nearest-even
__device__ __forceinline__ short f2bf(float x) {
    union { float f; unsigned int u; } v;
    v.f = x;
    unsigned int r = v.u + 0x7FFFu + ((v.u >> 16) & 1u);
    return (short)(r >> 16);
}

// D[16x16] = A[16x32] * B[32x16] + C.  A lane: row=l&15, k=(l>>4)*8+j.
// B lane: col=l&15, k=(l>>4)*8+j.  D lane: col=l&15, row=(l>>4)*4+reg.
__device__ __forceinline__ f32x4 mfma_bf16(bf16x8 a, bf16x8 b, f32x4 c) {
    return __builtin_amdgcn_mfma_f32_16x16x32_bf16(a, b, c, 0, 0, 0);
}

// ---------------------------------------------------------------------------
// w_o [1024][1024] f32 -> bf16 B-frag-major (2MB, the only d_ws use).
// ---------------------------------------------------------------------------
__global__ void wo_conv_kernel(const float* __restrict__ wo, short* __restrict__ wof) {
    const int t = blockIdx.x * 256 + threadIdx.x;   // 0..131071
    const int col = t >> 7, k8 = t & 127;
    const float* p = wo + (size_t)col * 1024 + k8 * 8;
    float4 a0 = *(const float4*)p;
    float4 a1 = *(const float4*)(p + 4);
    bf16x8 v;
    v[0]=f2bf(a0.x); v[1]=f2bf(a0.y); v[2]=f2bf(a0.z); v[3]=f2bf(a0.w);
    v[4]=f2bf(a1.x); v[5]=f2bf(a1.y); v[6]=f2bf(a1.z); v[7]=f2bf(a1.w);
    *(bf16x8*)(wof + ((col >> 4) * 16384 + k8 * 128 + (col & 15) * 8)) = v;
}

// ---------------------------------------------------------------------------
// Projection GEMM: C[row,col] = sum_k A[row,k]*W[col,k] + bias[col]
// MODE 0: Q (KDIM=1024, *QSCALE, -> Q A-frag)   MODE 1: K (768, -> K B-frag)
// MODE 2: V (768, -> V B-frag, m-as-K)
// ---------------------------------------------------------------------------
template <int MODE>
__global__ __launch_bounds__(256, 2) void proj_kernel(
    const float* __restrict__ Ain, const float* __restrict__ W,
    const float* __restrict__ bias, short* __restrict__ outb)
{
    constexpr int KDIM = (MODE == 1 || MODE == 2) ? 768 : 1024;
    __shared__ short Alds[128 * 64];
    __shared__ short Wlds[128 * 64];

    const int tid  = threadIdx.x;
    const int lane = tid & 63;
    const int g = lane >> 4, c = lane & 15;
    const int wid = tid >> 6;
    const int wm = wid >> 1, wn = wid & 1;
    const int bn = blockIdx.x, bm = blockIdx.y;

    const int srow = tid >> 3;
    const int scol = (tid & 7) * 8;

    f32x4 acc[4][4] = {};

    for (int kt = 0; kt < KDIM / 64; ++kt) {
        const int k0 = kt * 64;
        __syncthreads();
        #pragma unroll
        for (int p = 0; p < 4; ++p) {
            const int r = p * 32 + srow;
            bf16x8 av, wv;
            {
                const float* ap = Ain + (size_t)(bm * 128 + r) * KDIM + k0 + scol;
                float4 a0 = *(const float4*)ap;
                float4 a1 = *(const float4*)(ap + 4);
                av[0]=f2bf(a0.x); av[1]=f2bf(a0.y); av[2]=f2bf(a0.z); av[3]=f2bf(a0.w);
                av[4]=f2bf(a1.x); av[5]=f2bf(a1.y); av[6]=f2bf(a1.z); av[7]=f2bf(a1.w);
            }
            {
                const float* wp = W + (size_t)(bn * 128 + r) * KDIM + k0 + scol;
                float4 w0 = *(const float4*)wp;
                float4 w1 = *(const float4*)(wp + 4);
                wv[0]=f2bf(w0.x); wv[1]=f2bf(w0.y); wv[2]=f2bf(w0.z); wv[3]=f2bf(w0.w);
                wv[4]=f2bf(w1.x); wv[5]=f2bf(w1.y); wv[6]=f2bf(w1.z); wv[7]=f2bf(w1.w);
            }
            const int byt = (r * 128 + scol * 2) ^ ((r & 7) << 4);
            *(bf16x8*)((char*)Alds + byt) = av;
            *(bf16x8*)((char*)Wlds + byt) = wv;
        }
        __syncthreads();
        #pragma unroll
        for (int kc = 0; kc < 2; ++kc) {
            bf16x8 af[4], bfr[4];
            #pragma unroll
            for (int t = 0; t < 4; ++t) {
                const int ra = wm * 64 + t * 16 + c;
                af[t]  = *(const bf16x8*)((const char*)Alds +
                          ((ra * 128 + (kc * 32 + g * 8) * 2) ^ ((ra & 7) << 4)));
                const int rb = wn * 64 + t * 16 + c;
                bfr[t] = *(const bf16x8*)((const char*)Wlds +
                          ((rb * 128 + (kc * 32 + g * 8) * 2) ^ ((rb & 7) << 4)));
            }
            #pragma unroll
            for (int i = 0; i < 4; ++i)
                #pragma unroll
                for (int j = 0; j < 4; ++j)
                    acc[i][j] = mfma_bf16(af[i], bfr[j], acc[i][j]);
        }
    }

    #pragma unroll
    for (int j = 0; j < 4; ++j) {
        const int col = bn * 128 + wn * 64 + j * 16 + c;
        const float bv = bias[col];
        #pragma unroll
        for (int i = 0; i < 4; ++i) {
            #pragma unroll
            for (int r = 0; r < 4; ++r) {
                const int row = bm * 128 + wm * 64 + i * 16 + g * 4 + r;
                float v = acc[i][j][r] + bv;
                if constexpr (MODE == 0) v *= QSCALE;
                const int b = row >> 10, s = row & 1023;
                const int h = col >> 6,  d = col & 63;
                const size_t base = (size_t)(b * 16 + h) * 65536;
                size_t idx;
                if constexpr (MODE == 0)       // A-frag: [ntile][kc][g][c][j]
                    idx = base + (size_t)((s >> 4) * 1024 + (d >> 5) * 512 +
                          ((d >> 3) & 3) * 128 + (s & 15) * 8 + (d & 7));
                else if constexpr (MODE == 1)  // B-frag: [mtile][dchunk][c][j]
                    idx = base + (size_t)((s >> 4) * 1024 + (d >> 3) * 128 +
                          (s & 15) * 8 + (d & 7));
                else                           // V B-frag: [m32][dtile][g][c][j]
                    idx = base + (size_t)((s >> 5) * 2048 + (d >> 4) * 512 +
                          ((s >> 3) & 3) * 128 + (d & 15) * 8 + (s & 7));
                outb[idx] = f2bf(v);
            }
        }
    }
}

// ---------------------------------------------------------------------------
// Cooperative attention + fused O-projection.
// Block = (batch b = bid&7, 32-row q-tile qt = bid>>3), 512 threads (8 waves),
// grid 256 (1 block/CU).  Wave w owns score cols [w*128,+128), all 32 rows.
// Deferred-normalization softmax; per-wave O slots (no atomics); next-head
// Q/K prefetch before barrier 1; two barriers per head.
// ---------------------------------------------------------------------------
__global__ __launch_bounds__(512, 2) void attn_kernel(
    const short* Qf, const short* Kf, const short* Vf,
    const short* Wof, const float* bo, float* outp)
{
    __shared__ alignas(16) short Ohlds[32 * 1024];    // 64KB attn out, swizzled
    __shared__ alignas(16) short pbufs[8 * 32 * 40];  // 20.5KB bf16 P bounce
    __shared__ alignas(16) float oasl[8][32][68];     // 69.6KB per-wave O slots
    __shared__ alignas(16) float red[2][16][8];       // 1KB row-sum partials

    const int tid  = threadIdx.x;
    const int lane = tid & 63;
    const int w = tid >> 6;                  // 0..7
    const int g = lane >> 4, c = lane & 15;
    const int b = blockIdx.x & 7, qt = blockIdx.x >> 3;   // XCD-friendly split

    f32x4 am[2][8] = {};  // sum over heads of normalized P (attn.mean)

    // prologue: head-0 Q frags + first PF K frags (kc=0)
    bf16x8 qfr[2][2], kA[8];
    {
        const size_t hb0 = (size_t)(b * 16) * 65536;
        #pragma unroll
        for (int at = 0; at < 2; ++at)
            #pragma unroll
            for (int kc = 0; kc < 2; ++kc)
                qfr[at][kc] = *(const bf16x8*)(Qf + hb0 +
                    (size_t)((qt * 2 + at) * 1024 + kc * 512 + g * 128 + c * 8));
        #pragma unroll
        for (int mt = 0; mt < PF; ++mt)
            kA[mt] = *(const bf16x8*)(Kf + hb0 +
                (size_t)((w * 8 + mt) * 1024 + g * 128 + c * 8));
    }

    for (int h = 0; h < 16; ++h) {
        const size_t hb = (size_t)(b * 16 + h) * 65536;

        // finish K loads for this head (batched issue, then MFMAs)
        bf16x8 kB[8];
        #pragma unroll
        for (int mt = PF; mt < 8; ++mt)
            kA[mt] = *(const bf16x8*)(Kf + hb +
                (size_t)((w * 8 + mt) * 1024 + g * 128 + c * 8));
        #pragma unroll
        for (int mt = 0; mt < 8; ++mt)
            kB[mt] = *(const bf16x8*)(Kf + hb +
                (size_t)((w * 8 + mt) * 1024 + (4 + g) * 128 + c * 8));

        f32x4 p[2][8] = {};
        #pragma unroll
        for (int mt = 0; mt < 8; ++mt) {
            p[0][mt] = mfma_bf16(qfr[0][0], kA[mt], p[0][mt]);
            p[1][mt] = mfma_bf16(qfr[1][0], kA[mt], p[1][mt]);
        }
        #pragma unroll
        for (int mt = 0; mt < 8; ++mt) {
            p[0][mt] = mfma_bf16(qfr[0][1], kB[mt], p[0][mt]);
            p[1][mt] = mfma_bf16(qfr[1][1], kB[mt], p[1][mt]);
        }

        // exp2 (clamped) + per-lane partial row sums
        f32x4 rs[2] = {};
        #pragma unroll
        for (int at = 0; at < 2; ++at)
            #pragma unroll
            for (int mt = 0; mt < 8; ++mt) {
                f32x4 v = p[at][mt];
                #pragma unroll
                for (int r = 0; r < 4; ++r)
                    v[r] = exp2f(fminf(fmaxf(v[r], -60.f), 60.f));
                p[at][mt] = v;
                rs[at] += v;
            }
        #pragma unroll
        for (int off = 1; off < 16; off <<= 1)
            #pragma unroll
            for (int at = 0; at < 2; ++at)
                #pragma unroll
                for (int r = 0; r < 4; ++r)
                    rs[at][r] += __shfl_xor(rs[at][r], off);
        if (c == 0) {
            #pragma unroll
            for (int at = 0; at < 2; ++at)
                #pragma unroll
                for (int r = 0; r < 4; ++r)
                    red[at][g * 4 + r][w] = rs[at][r];
        }

        // PV on UNNORMALIZED P: V loads hoisted above the bf16 bounce
        short* pbs = pbufs + w * 1280;
        f32x4 oa[2][4] = {};
        #pragma unroll
        for (int ks = 0; ks < 4; ++ks) {
            bf16x8 vfr[4];
            #pragma unroll
            for (int dt = 0; dt < 4; ++dt)
                vfr[dt] = *(const bf16x8*)(Vf + hb +
                    (size_t)(((w * 4 + ks) * 4 + dt) * 512 + g * 128 + c * 8));
            #pragma unroll
            for (int at = 0; at < 2; ++at)
                #pragma unroll
                for (int m2 = 0; m2 < 2; ++m2)
                    #pragma unroll
                    for (int r = 0; r < 4; ++r)
                        pbs[(at * 16 + g * 4 + r) * 40 + m2 * 16 + c] =
                            f2bf(p[at][ks * 2 + m2][r]);
            asm volatile("s_waitcnt lgkmcnt(0)" ::: "memory");
            bf16x8 pa[2];
            #pragma unroll
            for (int at = 0; at < 2; ++at)
                pa[at] = *(const bf16x8*)&pbs[(at * 16 + c) * 40 + g * 8];
            #pragma unroll
            for (int dt = 0; dt < 4; ++dt) {
                oa[0][dt] = mfma_bf16(pa[0], vfr[dt], oa[0][dt]);
                oa[1][dt] = mfma_bf16(pa[1], vfr[dt], oa[1][dt]);
            }
        }
        // per-wave O slot (plain stores, no atomics)
        #pragma unroll
        for (int at = 0; at < 2; ++at)
            #pragma unroll
            for (int dt = 0; dt < 4; ++dt)
                #pragma unroll
                for (int r = 0; r < 4; ++r)
                    oasl[w][at * 16 + g * 4 + r][dt * 16 + c] = oa[at][dt][r];

        // prefetch next head's Q frags + first PF K frags (hide under barrier)
        if (h < 15) {
            const size_t hbN = hb + 65536;
            #pragma unroll
            for (int at = 0; at < 2; ++at)
                #pragma unroll
                for (int kc = 0; kc < 2; ++kc)
                    qfr[at][kc] = *(const bf16x8*)(Qf + hbN +
                        (size_t)((qt * 2 + at) * 1024 + kc * 512 + g * 128 + c * 8));
            #pragma unroll
            for (int mt = 0; mt < PF; ++mt)
                kA[mt] = *(const bf16x8*)(Kf + hbN +
                    (size_t)((w * 8 + mt) * 1024 + g * 128 + c * 8));
        }

        __syncthreads();   // barrier 1: red + oasl visible

        // per-lane rinv + attn-mean accumulation (p still in registers)
        #pragma unroll
        for (int at = 0; at < 2; ++at) {
            f32x4 rv;
            #pragma unroll
            for (int r = 0; r < 4; ++r) {
                f32x4 s0 = *(const f32x4*)&red[at][g * 4 + r][0];
                f32x4 s1 = *(const f32x4*)&red[at][g * 4 + r][4];
                f32x4 ss = s0 + s1;
                rv[r] = 1.0f / (ss[0] + ss[1] + ss[2] + ss[3]);
            }
            #pragma unroll
            for (int mt = 0; mt < 8; ++mt)
                am[at][mt] += p[at][mt] * rv;
        }

        // O tree-sum over 8 wave slots + normalize + stage to Ohlds
        {
            const int zn = tid >> 4, zd = (tid & 15) * 4;   // zn 0..31
            const int zh = zn >> 4, zr = zn & 15;
            f32x4 s0 = *(const f32x4*)&red[zh][zr][0];
            f32x4 s1 = *(const f32x4*)&red[zh][zr][4];
            f32x4 ss = s0 + s1;
            const float inv = 1.0f / (ss[0] + ss[1] + ss[2] + ss[3]);
            f32x4 ov = {0.f, 0.f, 0.f, 0.f};
            #pragma unroll
            for (int i = 0; i < 8; ++i)
                ov += *(const f32x4*)&oasl[i][zn][zd];
            s16x4 pk;
            pk[0] = f2bf(ov[0] * inv); pk[1] = f2bf(ov[1] * inv);
            pk[2] = f2bf(ov[2] * inv); pk[3] = f2bf(ov[3] * inv);
            unsigned byt = (unsigned)(zn * 2048 + (h * 64 + zd) * 2);
            byt ^= (unsigned)((zn & 7) << 4);          // XOR swizzle
            *(s16x4*)((char*)Ohlds + byt) = pk;
        }

        __syncthreads();   // barrier 2: reads done before next head's writes
    }

    // ---- all blocks done reading qf/kf/vf hosted in d_out ----
    cg::this_grid().sync();

    // attn.mean(heads) -> out1 (clobbers qf/kf hosting; frees am)
    float* aout = outp + 8388608 + (size_t)b * 1048576;
    #pragma unroll
    for (int at = 0; at < 2; ++at)
        #pragma unroll
        for (int mt = 0; mt < 8; ++mt)
            #pragma unroll
            for (int r = 0; r < 4; ++r) {
                const int n = qt * 32 + at * 16 + g * 4 + r;
                const int m = w * 128 + mt * 16 + c;
                aout[(size_t)n * 1024 + m] = am[at][mt][r] * 0.0625f;
            }

    // tail GEMM: out[32 rows][1024] = Ohlds(32x1024) @ w_o^T + b_o.
    // wave w: cols w*128..+128, both 16-row subtiles (clobbers vf hosting).
    f32x4 acc2[2][8] = {};
    for (int kt = 0; kt < 32; ++kt) {
        bf16x8 afr[2];
        #pragma unroll
        for (int at = 0; at < 2; ++at) {
            const int row = at * 16 + c;
            unsigned byt = (unsigned)(row * 2048 + (kt * 32 + g * 8) * 2);
            byt ^= (unsigned)((row & 7) << 4);
            afr[at] = *(const bf16x8*)((const char*)Ohlds + byt);
        }
        #pragma unroll
        for (int ct = 0; ct < 8; ++ct) {
            bf16x8 bfr = *(const bf16x8*)(Wof +
                ((w * 8 + ct) * 16384 + (kt * 4 + g) * 128 + c * 8));
            acc2[0][ct] = mfma_bf16(afr[0], bfr, acc2[0][ct]);
            acc2[1][ct] = mfma_bf16(afr[1], bfr, acc2[1][ct]);
        }
    }
    #pragma unroll
    for (int ct = 0; ct < 8; ++ct) {
        const int col = w * 128 + ct * 16 + c;
        const float bv = bo[col];
        #pragma unroll
        for (int at = 0; at < 2; ++at)
            #pragma unroll
            for (int r = 0; r < 4; ++r) {
                const int n = qt * 32 + at * 16 + g * 4 + r;
                outp[(size_t)(b * 1024 + n) * 1024 + col] = acc2[at][ct][r] + bv;
            }
    }
}

extern "C" void kernel_launch(void* const* d_in, const int* in_sizes, int n_in,
                              void* d_out, int out_size, void* d_ws, size_t ws_size,
                              hipStream_t stream)
{
    (void)in_sizes; (void)n_in; (void)out_size; (void)ws_size;
    const float* query = (const float*)d_in[0];
    const float* key   = (const float*)d_in[1];
    const float* value = (const float*)d_in[2];
    const float* w_q = (const float*)d_in[3];
    const float* b_q = (const float*)d_in[4];
    const float* w_k = (const float*)d_in[5];
    const float* b_k = (const float*)d_in[6];
    const float* w_v = (const float*)d_in[7];
    const float* b_v = (const float*)d_in[8];
    const float* w_o = (const float*)d_in[9];
    const float* b_o = (const float*)d_in[10];

    float* out = (float*)d_out;              // out0 [0,8M) floats; out1 [8M,16M)
    short* vf  = (short*)d_out;              // V frags hosted in out0 (16.78MB)
    short* qf  = (short*)(out + 8388608);    // Q frags hosted in out1 lower half
    short* kf  = qf + 8388608;               // K frags hosted in out1 upper half
    short* wof = (short*)d_ws;               // w_o bf16 frags (2MB — only ws use)

    wo_conv_kernel<<<dim3(512), 256, 0, stream>>>(w_o, wof);

    dim3 pgrid(8, 64);
    proj_kernel<0><<<pgrid, 256, 0, stream>>>(query, w_q, b_q, qf);
    proj_kernel<1><<<pgrid, 256, 0, stream>>>(key,   w_k, b_k, kf);
    proj_kernel<2><<<pgrid, 256, 0, stream>>>(value, w_v, b_v, vf);

    void* args[] = { (void*)&qf, (void*)&kf, (void*)&vf,
                     (void*)&wof, (void*)&b_o, (void*)&out };
    hipLaunchCooperativeKernel(attn_kernel, dim3(256), dim3(512), args, 0u, stream);
}